// Round 14
// baseline (251.370 us; speedup 1.0000x reference)
//
#include <hip/hip_runtime.h>

typedef unsigned short u16;
typedef __attribute__((ext_vector_type(8))) short short8;
typedef __attribute__((ext_vector_type(4))) float f32x4;
typedef __attribute__((ext_vector_type(2))) unsigned u32x2;
typedef __attribute__((ext_vector_type(4))) unsigned u32x4;

#define LOG2E 1.44269504088896340736f

__device__ __forceinline__ u16 f2bf(float f) {
    unsigned u = __float_as_uint(f);
    u += 0x7fffu + ((u >> 16) & 1u);
    return (u16)(u >> 16);
}

__device__ __forceinline__ void async_cp16(const void* g, void* l) {
    __builtin_amdgcn_global_load_lds(
        (const __attribute__((address_space(1))) unsigned*)g,
        (__attribute__((address_space(3))) unsigned*)l, 16, 0, 0);
}

// pack hi16(a), hi16(b) -> (b_hi<<16)|a_hi  : single v_perm_b32 (truncation)
__device__ __forceinline__ unsigned pack_trunc(float a, float b) {
    return __builtin_amdgcn_perm(__float_as_uint(b), __float_as_uint(a), 0x07060302u);
}

// ---------------------------------------------------------------------------
// Kernel 1: cast x and the 4 weight matrices to bf16.
// ---------------------------------------------------------------------------
__global__ void cast_all(const float4* __restrict__ x,
                         const float4* __restrict__ wq, const float4* __restrict__ wk,
                         const float4* __restrict__ wv, const float4* __restrict__ wo,
                         uint2* __restrict__ xb, uint2* __restrict__ wqkv,
                         uint2* __restrict__ wob) {
    long long g = (long long)blockIdx.x * blockDim.x + threadIdx.x;
    const long long XG = (8192LL * 1024) / 4;
    const long long WN = (1024LL * 1024) / 4;
    float4 v;
    uint2* dst;
    if (g < XG) {
        v = x[g];
        dst = xb + g;
    } else {
        long long t = g - XG;
        int s = (int)(t / WN);
        long long r = t - (long long)s * WN;
        const float4* src = (s == 0) ? wq : (s == 1) ? wk : (s == 2) ? wv : wo;
        v = src[r];
        dst = (s < 3) ? (wqkv + (long long)s * WN + r) : (wob + r);
    }
    uint2 p;
    p.x = (unsigned)f2bf(v.x) | ((unsigned)f2bf(v.y) << 16);
    p.y = (unsigned)f2bf(v.z) | ((unsigned)f2bf(v.w) << 16);
    *dst = p;
}

// ---------------------------------------------------------------------------
// NT GEMM v15: 128x128 tile, BK=64, 4 waves — now with the attn-style
// double-buffered single-barrier loop (proven v4-v14): preload tile 0;
// per step {sync(full drain) -> issue next tile into buf^1 -> compute buf}.
// vs the old {stage; sync; compute; sync}: barrier events 32 -> 16 and each
// step's staging latency now hides under the PREVIOUS step's MFMA phase
// (was fully serial). Full vmcnt(0) drain at each sync preserves the
// sibling-block convoy (same-m blocks share A-panels on one XCD after the
// axis swap), which rounds 9-11 proved is load-bearing for L2 sharing.
// LDS 64KB/block (2buf x (As+Bs) x 16KB); 2 blocks/CU = 128 <= 160KB, no
// occupancy change (m132's BK-unroll regression was an occupancy loss that
// does not apply here). Compute body, swizzle, epilogues unchanged.
// MODE 0: QKV epilogue (Q pre-scaled by SCALE*LOG2E); MODE 1: proj + bias.
// Grid: x = m-tile (fastest) so XCD = m-tile % 8 owns L2-resident A-panels.
// ---------------------------------------------------------------------------
template <int MODE>
__global__ __launch_bounds__(256, 2) void gemm_nt(
    const u16* __restrict__ A, const u16* __restrict__ Bw,
    u16* __restrict__ Qo, u16* __restrict__ Ko, u16* __restrict__ Vto,
    float* __restrict__ Fo, const float* __restrict__ bias, int K) {
    __shared__ u16 As[2][128 * 64];
    __shared__ u16 Bs[2][128 * 64];

    const int tid = threadIdx.x;
    const int lane = tid & 63, wave = tid >> 6;
    const int wm = wave >> 1, wn = wave & 1;
    const int quad = lane >> 4, l16 = lane & 15;
    const long long m0 = (long long)blockIdx.x * 128;  // m fastest -> XCD = m-tile%8
    const long long n0 = (long long)blockIdx.y * 128;

    f32x4 acc[4][4];
#pragma unroll
    for (int i = 0; i < 4; i++)
#pragma unroll
        for (int j = 0; j < 4; j++) acc[i][j] = (f32x4){0.f, 0.f, 0.f, 0.f};

    // staging geometry (loop-invariant): thread's row/chunk in the 128x64 tile
    // 4 issues per matrix per tile: ff = i*256+tid, row = ff>>3, chunk c = ff&7,
    // stored at swizzled chunk gc = c ^ (row&7).
#define GEMM_STAGE(BUF, KT)                                                     \
    do {                                                                        \
        _Pragma("unroll") for (int i = 0; i < 4; i++) {                         \
            int ff = i * 256 + tid;                                             \
            int row = ff >> 3, c = ff & 7;                                      \
            int gc = c ^ (row & 7);                                             \
            async_cp16(A + (m0 + row) * K + (KT) + gc * 8, &As[BUF][ff * 8]);   \
            async_cp16(Bw + (n0 + row) * K + (KT) + gc * 8, &Bs[BUF][ff * 8]);  \
        }                                                                       \
    } while (0)

    GEMM_STAGE(0, 0);  // preload tile 0

    for (int kt = 0; kt < K; kt += 64) {
        const int buf = (kt >> 6) & 1;
        __syncthreads();  // drains the stage issued last iteration (vmcnt 0)
        if (kt + 64 < K) GEMM_STAGE(buf ^ 1, kt + 64);
#pragma unroll
        for (int ks = 0; ks < 2; ks++) {
            short8 af[4], bfr[4];
#pragma unroll
            for (int t = 0; t < 4; t++) {
                int rowA = wm * 64 + t * 16 + l16;
                int ca = (ks * 4 + quad) ^ (rowA & 7);
                af[t] = *(const short8*)(&As[buf][rowA * 64 + ca * 8]);
                int rowB = wn * 64 + t * 16 + l16;
                int cb = (ks * 4 + quad) ^ (rowB & 7);
                bfr[t] = *(const short8*)(&Bs[buf][rowB * 64 + cb * 8]);
            }
#pragma unroll
            for (int i = 0; i < 4; i++)
#pragma unroll
                for (int j = 0; j < 4; j++)
                    acc[i][j] = __builtin_amdgcn_mfma_f32_16x16x32_bf16(
                        af[i], bfr[j], acc[i][j], 0, 0, 0);
        }
    }
#undef GEMM_STAGE

#pragma unroll
    for (int i = 0; i < 4; i++) {
        int mg = (int)m0 + wm * 64 + i * 16 + quad * 4;
#pragma unroll
        for (int j = 0; j < 4; j++) {
            int ng = (int)n0 + wn * 64 + j * 16 + l16;
            f32x4 v = acc[i][j];
            if (MODE == 0) {
                int which = ng >> 10;
                int wi = ng & 1023;
                int h = wi >> 6, d = wi & 63;
                int b = mg >> 11;
                int seq = mg & 2047;
                long long bh = (long long)(b * 16 + h);
                if (which == 0) {
                    const float QS = 0.125f * LOG2E;  // fold softmax log2e here
                    u16* dst = Qo + (bh * 2048 + seq) * 64 + d;
#pragma unroll
                    for (int r = 0; r < 4; r++) dst[r * 64] = f2bf(v[r] * QS);
                } else if (which == 1) {
                    u16* dst = Ko + (bh * 2048 + seq) * 64 + d;
#pragma unroll
                    for (int r = 0; r < 4; r++) dst[r * 64] = f2bf(v[r]);
                } else {
                    u16* dst = Vto + (bh * 64 + d) * 2048 + seq;
                    uint2 p;
                    p.x = (unsigned)f2bf(v[0]) | ((unsigned)f2bf(v[1]) << 16);
                    p.y = (unsigned)f2bf(v[2]) | ((unsigned)f2bf(v[3]) << 16);
                    *(uint2*)dst = p;
                }
            } else {
                float* dst = Fo + (long long)mg * 1024 + ng;
                float bb = bias[ng];
#pragma unroll
                for (int r = 0; r < 4; r++) dst[r * 1024] = v[r] + bb;
            }
        }
    }
}

// ---------------------------------------------------------------------------
// Flash attention v14 (unchanged — best measured: 80.3us, FETCH 36MB).
// KVBLK=128 per barrier as two sequential 64-row halves of the v11 body;
// full vmcnt(0) drain each step preserves the sibling-block convoy that
// makes bh-grouped XCD L2 sharing work. P in registers via
// permlane32/16_swap; PV at K=32.
// Grid (64 bh, 8 q-tiles), 512 threads = 8 waves; wave owns 32 q rows.
// ---------------------------------------------------------------------------
__global__ __launch_bounds__(512, 4) void attn(
    const u16* __restrict__ Q, const u16* __restrict__ Kb,
    const u16* __restrict__ Vt, u16* __restrict__ O) {
    __shared__ u16 Ks[2][128 * 64];
    __shared__ u16 Vs[2][128 * 64];

    const int tid = threadIdx.x;
    const int lane = tid & 63, wave = tid >> 6;
    const int quad = lane >> 4, l16 = lane & 15;
    const int qt = blockIdx.y, bh = blockIdx.x;  // bh fastest -> XCD = bh%8

    const u16* Qh = Q + (long long)bh * 2048 * 64;
    const u16* Kh = Kb + (long long)bh * 2048 * 64;
    const u16* Vh = Vt + (long long)bh * 64 * 2048;
    const int q0 = qt * 256 + wave * 32;

    // staging geometry: 512 threads x 16B = 8KB = one 64-row half per issue
    const int srow = tid >> 3, sc = tid & 7;
    const int sgc = sc ^ (srow & 7);
    const u16* Kg = Kh + srow * 64 + sgc * 8;               // + kt2*8192 + h*4096
    const u16* Vg = Vh + (long long)srow * 2048 + sgc * 8;  // + kt2*128  + h*64

    // Q fragments (register-resident; Q pre-scaled by SCALE*LOG2E)
    short8 qf[2][2];
#pragma unroll
    for (int tm = 0; tm < 2; tm++)
#pragma unroll
        for (int ks = 0; ks < 2; ks++)
            qf[tm][ks] = *(const short8*)(Qh + (q0 + tm * 16 + l16) * 64 + ks * 32 + quad * 8);

    // loop-invariant LDS offsets (u16 units): K/V fragment reads (16x16x32)
    // row indices are within-half [0,64), matching the per-64-row swizzle.
    int kvo[2][4];
#pragma unroll
    for (int ks = 0; ks < 2; ks++)
#pragma unroll
        for (int tn = 0; tn < 4; tn++) {
            int row = tn * 16 + l16;
            kvo[ks][tn] = row * 64 + (((ks * 4 + quad) ^ (row & 7)) * 8);
        }

    f32x4 o_acc[2][4], lacc[2];
#pragma unroll
    for (int tm = 0; tm < 2; tm++) {
        lacc[tm] = (f32x4){0.f, 0.f, 0.f, 0.f};
#pragma unroll
        for (int tn = 0; tn < 4; tn++) o_acc[tm][tn] = (f32x4){0.f, 0.f, 0.f, 0.f};
    }
    const float NEGC = -12.0f * LOG2E;  // static max M=12, log2 domain
    const short BF1 = (short)0x3F80;    // bf16 1.0
    const short8 ones = {BF1, BF1, BF1, BF1, BF1, BF1, BF1, BF1};

    // preload tile 0 (both halves: 4 issues)
    async_cp16(Kg, &Ks[0][tid * 8]);
    async_cp16(Kg + 4096, &Ks[0][4096 + tid * 8]);
    async_cp16(Vg, &Vs[0][tid * 8]);
    async_cp16(Vg + 64, &Vs[0][4096 + tid * 8]);

// one 64-row half: identical to the v11 step body (QK -> exp/pack ->
// permlane k-regroup -> PV @ K=32), reading K/V at base KC/VC.
#define ATTN_HALF(KC, VC)                                                               \
    do {                                                                                \
        const u16* Kc = (KC);                                                           \
        const u16* Vc = (VC);                                                           \
        f32x4 s[2][4];                                                                  \
        _Pragma("unroll") for (int tm = 0; tm < 2; tm++)                                \
            _Pragma("unroll") for (int tn = 0; tn < 4; tn++)                            \
                s[tm][tn] = (f32x4){NEGC, NEGC, NEGC, NEGC};                            \
        _Pragma("unroll") for (int ks = 0; ks < 2; ks++) {                              \
            short8 kf[4];                                                               \
            _Pragma("unroll") for (int tn = 0; tn < 4; tn++)                            \
                kf[tn] = *(const short8*)(&Kc[kvo[ks][tn]]);                            \
            _Pragma("unroll") for (int tm = 0; tm < 2; tm++)                            \
                _Pragma("unroll") for (int tn = 0; tn < 4; tn++)                        \
                    s[tm][tn] = __builtin_amdgcn_mfma_f32_16x16x32_bf16(                \
                        kf[tn], qf[tm][ks], s[tm][tn], 0, 0, 0);                        \
        }                                                                               \
        short8 pa[2][2];                                                                \
        _Pragma("unroll") for (int tm = 0; tm < 2; tm++) {                              \
            unsigned W[4][2];                                                           \
            _Pragma("unroll") for (int tn = 0; tn < 4; tn++) {                          \
                f32x4 sv = s[tm][tn];                                                   \
                float e0 = __builtin_amdgcn_exp2f(sv[0]);                               \
                float e1 = __builtin_amdgcn_exp2f(sv[1]);                               \
                float e2 = __builtin_amdgcn_exp2f(sv[2]);                               \
                float e3 = __builtin_amdgcn_exp2f(sv[3]);                               \
                W[tn][0] = pack_trunc(e0, e1);                                          \
                W[tn][1] = pack_trunc(e2, e3);                                          \
            }                                                                           \
            _Pragma("unroll") for (int t2 = 0; t2 < 2; t2++)                            \
                _Pragma("unroll") for (int w = 0; w < 2; w++) {                         \
                    u32x2 r = __builtin_amdgcn_permlane32_swap(                         \
                        W[2 * t2][w], W[2 * t2 + 1][w], false, false);                  \
                    W[2 * t2][w] = r[0];                                                \
                    W[2 * t2 + 1][w] = r[1];                                            \
                }                                                                       \
            _Pragma("unroll") for (int t2 = 0; t2 < 2; t2++)                            \
                _Pragma("unroll") for (int w = 0; w < 2; w++) {                         \
                    u32x2 r = __builtin_amdgcn_permlane16_swap(                         \
                        W[2 * t2][w], W[2 * t2 + 1][w], false, false);                  \
                    W[2 * t2][w] = r[0];                                                \
                    W[2 * t2 + 1][w] = r[1];                                            \
                }                                                                       \
            _Pragma("unroll") for (int ks = 0; ks < 2; ks++) {                          \
                u32x4 pd;                                                               \
                pd[0] = W[2 * ks][0];                                                   \
                pd[1] = W[2 * ks][1];                                                   \
                pd[2] = W[2 * ks + 1][0];                                               \
                pd[3] = W[2 * ks + 1][1];                                               \
                pa[tm][ks] = *(short8*)&pd;                                             \
            }                                                                           \
        }                                                                               \
        _Pragma("unroll") for (int ks = 0; ks < 2; ks++) {                              \
            short8 vf[4];                                                               \
            _Pragma("unroll") for (int tn = 0; tn < 4; tn++)                            \
                vf[tn] = *(const short8*)(&Vc[kvo[ks][tn]]);                            \
            lacc[0] = __builtin_amdgcn_mfma_f32_16x16x32_bf16(pa[0][ks], ones, lacc[0], 0, 0, 0); \
            lacc[1] = __builtin_amdgcn_mfma_f32_16x16x32_bf16(pa[1][ks], ones, lacc[1], 0, 0, 0); \
            _Pragma("unroll") for (int tn = 0; tn < 4; tn++) {                          \
                o_acc[0][tn] = __builtin_amdgcn_mfma_f32_16x16x32_bf16(                 \
                    pa[0][ks], vf[tn], o_acc[0][tn], 0, 0, 0);                          \
                o_acc[1][tn] = __builtin_amdgcn_mfma_f32_16x16x32_bf16(                 \
                    pa[1][ks], vf[tn], o_acc[1][tn], 0, 0, 0);                          \
            }                                                                           \
        }                                                                               \
    } while (0)

#define ATTN_STEP(KT2, BUF)                                                             \
    do {                                                                                \
        __syncthreads();                                                                \
        if ((KT2) < 15) {                                                               \
            async_cp16(Kg + ((KT2) + 1) * 8192, &Ks[(BUF) ^ 1][tid * 8]);               \
            async_cp16(Kg + ((KT2) + 1) * 8192 + 4096, &Ks[(BUF) ^ 1][4096 + tid * 8]); \
            async_cp16(Vg + ((KT2) + 1) * 128, &Vs[(BUF) ^ 1][tid * 8]);                \
            async_cp16(Vg + ((KT2) + 1) * 128 + 64, &Vs[(BUF) ^ 1][4096 + tid * 8]);    \
        }                                                                               \
        ATTN_HALF(&Ks[BUF][0], &Vs[BUF][0]);                                            \
        ATTN_HALF(&Ks[BUF][4096], &Vs[BUF][4096]);                                      \
    } while (0)

#pragma unroll 1
    for (int kt2 = 0; kt2 < 16; kt2 += 2) {
        ATTN_STEP(kt2, 0);
        ATTN_STEP(kt2 + 1, 1);
    }
#undef ATTN_STEP
#undef ATTN_HALF

    // O write: acc rows q = quad*4+r align between o_acc and lacc
    f32x4 linv[2];
#pragma unroll
    for (int tm = 0; tm < 2; tm++)
#pragma unroll
        for (int r = 0; r < 4; r++) linv[tm][r] = 1.0f / lacc[tm][r];

    const int b = bh >> 4, h = bh & 15;
#pragma unroll
    for (int tm = 0; tm < 2; tm++)
#pragma unroll
        for (int tn = 0; tn < 4; tn++) {
            int seq = q0 + tm * 16 + quad * 4;
            int c = h * 64 + tn * 16 + l16;
            u16* dst = O + ((long long)(b * 2048 + seq)) * 1024 + c;
#pragma unroll
            for (int r = 0; r < 4; r++)
                dst[r * 1024] = f2bf(o_acc[tm][tn][r] * linv[tm][r]);
        }
}

// ---------------------------------------------------------------------------
extern "C" void kernel_launch(void* const* d_in, const int* in_sizes, int n_in,
                              void* d_out, int out_size, void* d_ws, size_t ws_size,
                              hipStream_t stream) {
    const float* x = (const float*)d_in[0];
    const float* wq = (const float*)d_in[1];
    const float* wk = (const float*)d_in[2];
    const float* wv = (const float*)d_in[3];
    const float* wo = (const float*)d_in[4];
    const float* bo = (const float*)d_in[5];
    float* out = (float*)d_out;

    char* ws = (char*)d_ws;
    u16* xb   = (u16*)(ws);                        // 16 MB  [8192][1024]
    u16* wqkv = (u16*)(ws + (16LL << 20));         //  6 MB  [3072][1024]
    u16* wob  = (u16*)(ws + (22LL << 20));         //  2 MB  [1024][1024]
    u16* Qb   = (u16*)(ws + (24LL << 20));         // 16 MB  [64][2048][64]
    u16* Kbuf = (u16*)(ws + (40LL << 20));         // 16 MB  [64][2048][64]
    u16* Vt   = (u16*)(ws + (56LL << 20));         // 16 MB  [64][64][2048]
    u16* Ob   = (u16*)(ws + (72LL << 20));         // 16 MB  [8192][1024]

    cast_all<<<12288, 256, 0, stream>>>((const float4*)x, (const float4*)wq,
                                        (const float4*)wk, (const float4*)wv,
                                        (const float4*)wo, (uint2*)xb,
                                        (uint2*)wqkv, (uint2*)wob);

    dim3 g1(64, 24);  // m-tile fastest: XCD owns A-panels (L2-resident)
    gemm_nt<0><<<g1, 256, 0, stream>>>(xb, wqkv, Qb, Kbuf, Vt, nullptr, nullptr, 1024);

    dim3 g2(64, 8);   // bh fastest: all 8 q-tiles of a bh on one XCD
    attn<<<g2, 512, 0, stream>>>(Qb, Kbuf, Vt, Ob);

    dim3 g3(64, 8);   // m-tile fastest for proj GEMM too
    gemm_nt<1><<<g3, 256, 0, stream>>>(Ob, wob, nullptr, nullptr, nullptr, out, bo, 1024);
}

// Round 15
// 240.614 us; speedup vs baseline: 1.0447x; 1.0447x over previous
//
#include <hip/hip_runtime.h>

typedef unsigned short u16;
typedef __attribute__((ext_vector_type(8))) short short8;
typedef __attribute__((ext_vector_type(4))) float f32x4;
typedef __attribute__((ext_vector_type(2))) unsigned u32x2;
typedef __attribute__((ext_vector_type(4))) unsigned u32x4;

#define LOG2E 1.44269504088896340736f

__device__ __forceinline__ u16 f2bf(float f) {
    unsigned u = __float_as_uint(f);
    u += 0x7fffu + ((u >> 16) & 1u);
    return (u16)(u >> 16);
}

__device__ __forceinline__ void async_cp16(const void* g, void* l) {
    __builtin_amdgcn_global_load_lds(
        (const __attribute__((address_space(1))) unsigned*)g,
        (__attribute__((address_space(3))) unsigned*)l, 16, 0, 0);
}

// pack hi16(a), hi16(b) -> (b_hi<<16)|a_hi  : single v_perm_b32 (truncation)
__device__ __forceinline__ unsigned pack_trunc(float a, float b) {
    return __builtin_amdgcn_perm(__float_as_uint(b), __float_as_uint(a), 0x07060302u);
}

// ---------------------------------------------------------------------------
// Kernel 1: cast x and the 4 weight matrices to bf16.
// ---------------------------------------------------------------------------
__global__ void cast_all(const float4* __restrict__ x,
                         const float4* __restrict__ wq, const float4* __restrict__ wk,
                         const float4* __restrict__ wv, const float4* __restrict__ wo,
                         uint2* __restrict__ xb, uint2* __restrict__ wqkv,
                         uint2* __restrict__ wob) {
    long long g = (long long)blockIdx.x * blockDim.x + threadIdx.x;
    const long long XG = (8192LL * 1024) / 4;
    const long long WN = (1024LL * 1024) / 4;
    float4 v;
    uint2* dst;
    if (g < XG) {
        v = x[g];
        dst = xb + g;
    } else {
        long long t = g - XG;
        int s = (int)(t / WN);
        long long r = t - (long long)s * WN;
        const float4* src = (s == 0) ? wq : (s == 1) ? wk : (s == 2) ? wv : wo;
        v = src[r];
        dst = (s < 3) ? (wqkv + (long long)s * WN + r) : (wob + r);
    }
    uint2 p;
    p.x = (unsigned)f2bf(v.x) | ((unsigned)f2bf(v.y) << 16);
    p.y = (unsigned)f2bf(v.z) | ((unsigned)f2bf(v.w) << 16);
    *dst = p;
}

// ---------------------------------------------------------------------------
// NT GEMM (round-13 form, FINAL): 128x128 tile, BK=64, 4 waves, single
// buffer, global_load_lds. Round-14's dbuf variant regressed (+4us total):
// 64KB LDS hard-capped occupancy at 2 blocks/CU, trading away the implicit
// multi-block wave overlap (m114) the 32KB version kept (up to 5 blocks/CU
// LDS-wise; launch_bounds(256,2) is a register floor, not an occupancy cap).
// MODE 0: QKV epilogue (Q pre-scaled by SCALE*LOG2E); MODE 1: proj + bias.
// Grid: x = m-tile (fastest) so XCD = m-tile % 8 owns L2-resident A-panels.
// ---------------------------------------------------------------------------
template <int MODE>
__global__ __launch_bounds__(256, 2) void gemm_nt(
    const u16* __restrict__ A, const u16* __restrict__ Bw,
    u16* __restrict__ Qo, u16* __restrict__ Ko, u16* __restrict__ Vto,
    float* __restrict__ Fo, const float* __restrict__ bias, int K) {
    __shared__ u16 As[128 * 64];
    __shared__ u16 Bs[128 * 64];

    const int tid = threadIdx.x;
    const int lane = tid & 63, wave = tid >> 6;
    const int wm = wave >> 1, wn = wave & 1;
    const int quad = lane >> 4, l16 = lane & 15;
    const long long m0 = (long long)blockIdx.x * 128;  // m fastest -> XCD = m-tile%8
    const long long n0 = (long long)blockIdx.y * 128;

    f32x4 acc[4][4];
#pragma unroll
    for (int i = 0; i < 4; i++)
#pragma unroll
        for (int j = 0; j < 4; j++) acc[i][j] = (f32x4){0.f, 0.f, 0.f, 0.f};

    for (int kt = 0; kt < K; kt += 64) {
#pragma unroll
        for (int i = 0; i < 4; i++) {
            int ff = i * 256 + tid;
            int row = ff >> 3, c = ff & 7;
            int gc = c ^ (row & 7);
            async_cp16(A + (m0 + row) * K + kt + gc * 8, &As[ff * 8]);
            async_cp16(Bw + (n0 + row) * K + kt + gc * 8, &Bs[ff * 8]);
        }
        __syncthreads();
#pragma unroll
        for (int ks = 0; ks < 2; ks++) {
            short8 af[4], bfr[4];
#pragma unroll
            for (int t = 0; t < 4; t++) {
                int rowA = wm * 64 + t * 16 + l16;
                int ca = (ks * 4 + quad) ^ (rowA & 7);
                af[t] = *(const short8*)(&As[rowA * 64 + ca * 8]);
                int rowB = wn * 64 + t * 16 + l16;
                int cb = (ks * 4 + quad) ^ (rowB & 7);
                bfr[t] = *(const short8*)(&Bs[rowB * 64 + cb * 8]);
            }
#pragma unroll
            for (int i = 0; i < 4; i++)
#pragma unroll
                for (int j = 0; j < 4; j++)
                    acc[i][j] = __builtin_amdgcn_mfma_f32_16x16x32_bf16(
                        af[i], bfr[j], acc[i][j], 0, 0, 0);
        }
        __syncthreads();
    }

#pragma unroll
    for (int i = 0; i < 4; i++) {
        int mg = (int)m0 + wm * 64 + i * 16 + quad * 4;
#pragma unroll
        for (int j = 0; j < 4; j++) {
            int ng = (int)n0 + wn * 64 + j * 16 + l16;
            f32x4 v = acc[i][j];
            if (MODE == 0) {
                int which = ng >> 10;
                int wi = ng & 1023;
                int h = wi >> 6, d = wi & 63;
                int b = mg >> 11;
                int seq = mg & 2047;
                long long bh = (long long)(b * 16 + h);
                if (which == 0) {
                    const float QS = 0.125f * LOG2E;  // fold softmax log2e here
                    u16* dst = Qo + (bh * 2048 + seq) * 64 + d;
#pragma unroll
                    for (int r = 0; r < 4; r++) dst[r * 64] = f2bf(v[r] * QS);
                } else if (which == 1) {
                    u16* dst = Ko + (bh * 2048 + seq) * 64 + d;
#pragma unroll
                    for (int r = 0; r < 4; r++) dst[r * 64] = f2bf(v[r]);
                } else {
                    u16* dst = Vto + (bh * 64 + d) * 2048 + seq;
                    uint2 p;
                    p.x = (unsigned)f2bf(v[0]) | ((unsigned)f2bf(v[1]) << 16);
                    p.y = (unsigned)f2bf(v[2]) | ((unsigned)f2bf(v[3]) << 16);
                    *(uint2*)dst = p;
                }
            } else {
                float* dst = Fo + (long long)mg * 1024 + ng;
                float bb = bias[ng];
#pragma unroll
                for (int r = 0; r < 4; r++) dst[r * 1024] = v[r] + bb;
            }
        }
    }
}

// ---------------------------------------------------------------------------
// Flash attention v14 (FINAL — best measured: 80.3us, FETCH 36MB).
// KVBLK=128 per barrier as two sequential 64-row halves of the v11 body;
// full vmcnt(0) drain each step preserves the sibling-block convoy that
// makes bh-grouped XCD L2 sharing work (counted-vmcnt pipelines dissolved
// it twice: FETCH 142->211MB / 29->68MB, both slower). P in registers via
// permlane32/16_swap (QK C-frag k-regroup, no LDS round-trip); PV at K=32.
// Grid (64 bh, 8 q-tiles), 512 threads = 8 waves; wave owns 32 q rows.
// ---------------------------------------------------------------------------
__global__ __launch_bounds__(512, 4) void attn(
    const u16* __restrict__ Q, const u16* __restrict__ Kb,
    const u16* __restrict__ Vt, u16* __restrict__ O) {
    __shared__ u16 Ks[2][128 * 64];
    __shared__ u16 Vs[2][128 * 64];

    const int tid = threadIdx.x;
    const int lane = tid & 63, wave = tid >> 6;
    const int quad = lane >> 4, l16 = lane & 15;
    const int qt = blockIdx.y, bh = blockIdx.x;  // bh fastest -> XCD = bh%8

    const u16* Qh = Q + (long long)bh * 2048 * 64;
    const u16* Kh = Kb + (long long)bh * 2048 * 64;
    const u16* Vh = Vt + (long long)bh * 64 * 2048;
    const int q0 = qt * 256 + wave * 32;

    // staging geometry: 512 threads x 16B = 8KB = one 64-row half per issue
    const int srow = tid >> 3, sc = tid & 7;
    const int sgc = sc ^ (srow & 7);
    const u16* Kg = Kh + srow * 64 + sgc * 8;               // + kt2*8192 + h*4096
    const u16* Vg = Vh + (long long)srow * 2048 + sgc * 8;  // + kt2*128  + h*64

    // Q fragments (register-resident; Q pre-scaled by SCALE*LOG2E)
    short8 qf[2][2];
#pragma unroll
    for (int tm = 0; tm < 2; tm++)
#pragma unroll
        for (int ks = 0; ks < 2; ks++)
            qf[tm][ks] = *(const short8*)(Qh + (q0 + tm * 16 + l16) * 64 + ks * 32 + quad * 8);

    // loop-invariant LDS offsets (u16 units): K/V fragment reads (16x16x32)
    // row indices are within-half [0,64), matching the per-64-row swizzle.
    int kvo[2][4];
#pragma unroll
    for (int ks = 0; ks < 2; ks++)
#pragma unroll
        for (int tn = 0; tn < 4; tn++) {
            int row = tn * 16 + l16;
            kvo[ks][tn] = row * 64 + (((ks * 4 + quad) ^ (row & 7)) * 8);
        }

    f32x4 o_acc[2][4], lacc[2];
#pragma unroll
    for (int tm = 0; tm < 2; tm++) {
        lacc[tm] = (f32x4){0.f, 0.f, 0.f, 0.f};
#pragma unroll
        for (int tn = 0; tn < 4; tn++) o_acc[tm][tn] = (f32x4){0.f, 0.f, 0.f, 0.f};
    }
    const float NEGC = -12.0f * LOG2E;  // static max M=12, log2 domain
    const short BF1 = (short)0x3F80;    // bf16 1.0
    const short8 ones = {BF1, BF1, BF1, BF1, BF1, BF1, BF1, BF1};

    // preload tile 0 (both halves: 4 issues)
    async_cp16(Kg, &Ks[0][tid * 8]);
    async_cp16(Kg + 4096, &Ks[0][4096 + tid * 8]);
    async_cp16(Vg, &Vs[0][tid * 8]);
    async_cp16(Vg + 64, &Vs[0][4096 + tid * 8]);

// one 64-row half: identical to the v11 step body (QK -> exp/pack ->
// permlane k-regroup -> PV @ K=32), reading K/V at base KC/VC.
#define ATTN_HALF(KC, VC)                                                               \
    do {                                                                                \
        const u16* Kc = (KC);                                                           \
        const u16* Vc = (VC);                                                           \
        f32x4 s[2][4];                                                                  \
        _Pragma("unroll") for (int tm = 0; tm < 2; tm++)                                \
            _Pragma("unroll") for (int tn = 0; tn < 4; tn++)                            \
                s[tm][tn] = (f32x4){NEGC, NEGC, NEGC, NEGC};                            \
        _Pragma("unroll") for (int ks = 0; ks < 2; ks++) {                              \
            short8 kf[4];                                                               \
            _Pragma("unroll") for (int tn = 0; tn < 4; tn++)                            \
                kf[tn] = *(const short8*)(&Kc[kvo[ks][tn]]);                            \
            _Pragma("unroll") for (int tm = 0; tm < 2; tm++)                            \
                _Pragma("unroll") for (int tn = 0; tn < 4; tn++)                        \
                    s[tm][tn] = __builtin_amdgcn_mfma_f32_16x16x32_bf16(                \
                        kf[tn], qf[tm][ks], s[tm][tn], 0, 0, 0);                        \
        }                                                                               \
        short8 pa[2][2];                                                                \
        _Pragma("unroll") for (int tm = 0; tm < 2; tm++) {                              \
            unsigned W[4][2];                                                           \
            _Pragma("unroll") for (int tn = 0; tn < 4; tn++) {                          \
                f32x4 sv = s[tm][tn];                                                   \
                float e0 = __builtin_amdgcn_exp2f(sv[0]);                               \
                float e1 = __builtin_amdgcn_exp2f(sv[1]);                               \
                float e2 = __builtin_amdgcn_exp2f(sv[2]);                               \
                float e3 = __builtin_amdgcn_exp2f(sv[3]);                               \
                W[tn][0] = pack_trunc(e0, e1);                                          \
                W[tn][1] = pack_trunc(e2, e3);                                          \
            }                                                                           \
            _Pragma("unroll") for (int t2 = 0; t2 < 2; t2++)                            \
                _Pragma("unroll") for (int w = 0; w < 2; w++) {                         \
                    u32x2 r = __builtin_amdgcn_permlane32_swap(                         \
                        W[2 * t2][w], W[2 * t2 + 1][w], false, false);                  \
                    W[2 * t2][w] = r[0];                                                \
                    W[2 * t2 + 1][w] = r[1];                                            \
                }                                                                       \
            _Pragma("unroll") for (int t2 = 0; t2 < 2; t2++)                            \
                _Pragma("unroll") for (int w = 0; w < 2; w++) {                         \
                    u32x2 r = __builtin_amdgcn_permlane16_swap(                         \
                        W[2 * t2][w], W[2 * t2 + 1][w], false, false);                  \
                    W[2 * t2][w] = r[0];                                                \
                    W[2 * t2 + 1][w] = r[1];                                            \
                }                                                                       \
            _Pragma("unroll") for (int ks = 0; ks < 2; ks++) {                          \
                u32x4 pd;                                                               \
                pd[0] = W[2 * ks][0];                                                   \
                pd[1] = W[2 * ks][1];                                                   \
                pd[2] = W[2 * ks + 1][0];                                               \
                pd[3] = W[2 * ks + 1][1];                                               \
                pa[tm][ks] = *(short8*)&pd;                                             \
            }                                                                           \
        }                                                                               \
        _Pragma("unroll") for (int ks = 0; ks < 2; ks++) {                              \
            short8 vf[4];                                                               \
            _Pragma("unroll") for (int tn = 0; tn < 4; tn++)                            \
                vf[tn] = *(const short8*)(&Vc[kvo[ks][tn]]);                            \
            lacc[0] = __builtin_amdgcn_mfma_f32_16x16x32_bf16(pa[0][ks], ones, lacc[0], 0, 0, 0); \
            lacc[1] = __builtin_amdgcn_mfma_f32_16x16x32_bf16(pa[1][ks], ones, lacc[1], 0, 0, 0); \
            _Pragma("unroll") for (int tn = 0; tn < 4; tn++) {                          \
                o_acc[0][tn] = __builtin_amdgcn_mfma_f32_16x16x32_bf16(                 \
                    pa[0][ks], vf[tn], o_acc[0][tn], 0, 0, 0);                          \
                o_acc[1][tn] = __builtin_amdgcn_mfma_f32_16x16x32_bf16(                 \
                    pa[1][ks], vf[tn], o_acc[1][tn], 0, 0, 0);                          \
            }                                                                           \
        }                                                                               \
    } while (0)

#define ATTN_STEP(KT2, BUF)                                                             \
    do {                                                                                \
        __syncthreads();                                                                \
        if ((KT2) < 15) {                                                               \
            async_cp16(Kg + ((KT2) + 1) * 8192, &Ks[(BUF) ^ 1][tid * 8]);               \
            async_cp16(Kg + ((KT2) + 1) * 8192 + 4096, &Ks[(BUF) ^ 1][4096 + tid * 8]); \
            async_cp16(Vg + ((KT2) + 1) * 128, &Vs[(BUF) ^ 1][tid * 8]);                \
            async_cp16(Vg + ((KT2) + 1) * 128 + 64, &Vs[(BUF) ^ 1][4096 + tid * 8]);    \
        }                                                                               \
        ATTN_HALF(&Ks[BUF][0], &Vs[BUF][0]);                                            \
        ATTN_HALF(&Ks[BUF][4096], &Vs[BUF][4096]);                                      \
    } while (0)

#pragma unroll 1
    for (int kt2 = 0; kt2 < 16; kt2 += 2) {
        ATTN_STEP(kt2, 0);
        ATTN_STEP(kt2 + 1, 1);
    }
#undef ATTN_STEP
#undef ATTN_HALF

    // O write: acc rows q = quad*4+r align between o_acc and lacc
    f32x4 linv[2];
#pragma unroll
    for (int tm = 0; tm < 2; tm++)
#pragma unroll
        for (int r = 0; r < 4; r++) linv[tm][r] = 1.0f / lacc[tm][r];

    const int b = bh >> 4, h = bh & 15;
#pragma unroll
    for (int tm = 0; tm < 2; tm++)
#pragma unroll
        for (int tn = 0; tn < 4; tn++) {
            int seq = q0 + tm * 16 + quad * 4;
            int c = h * 64 + tn * 16 + l16;
            u16* dst = O + ((long long)(b * 2048 + seq)) * 1024 + c;
#pragma unroll
            for (int r = 0; r < 4; r++)
                dst[r * 1024] = f2bf(o_acc[tm][tn][r] * linv[tm][r]);
        }
}

// ---------------------------------------------------------------------------
extern "C" void kernel_launch(void* const* d_in, const int* in_sizes, int n_in,
                              void* d_out, int out_size, void* d_ws, size_t ws_size,
                              hipStream_t stream) {
    const float* x = (const float*)d_in[0];
    const float* wq = (const float*)d_in[1];
    const float* wk = (const float*)d_in[2];
    const float* wv = (const float*)d_in[3];
    const float* wo = (const float*)d_in[4];
    const float* bo = (const float*)d_in[5];
    float* out = (float*)d_out;

    char* ws = (char*)d_ws;
    u16* xb   = (u16*)(ws);                        // 16 MB  [8192][1024]
    u16* wqkv = (u16*)(ws + (16LL << 20));         //  6 MB  [3072][1024]
    u16* wob  = (u16*)(ws + (22LL << 20));         //  2 MB  [1024][1024]
    u16* Qb   = (u16*)(ws + (24LL << 20));         // 16 MB  [64][2048][64]
    u16* Kbuf = (u16*)(ws + (40LL << 20));         // 16 MB  [64][2048][64]
    u16* Vt   = (u16*)(ws + (56LL << 20));         // 16 MB  [64][64][2048]
    u16* Ob   = (u16*)(ws + (72LL << 20));         // 16 MB  [8192][1024]

    cast_all<<<12288, 256, 0, stream>>>((const float4*)x, (const float4*)wq,
                                        (const float4*)wk, (const float4*)wv,
                                        (const float4*)wo, (uint2*)xb,
                                        (uint2*)wqkv, (uint2*)wob);

    dim3 g1(64, 24);  // m-tile fastest: XCD owns A-panels (L2-resident)
    gemm_nt<0><<<g1, 256, 0, stream>>>(xb, wqkv, Qb, Kbuf, Vt, nullptr, nullptr, 1024);

    dim3 g2(64, 8);   // bh fastest: all 8 q-tiles of a bh on one XCD
    attn<<<g2, 512, 0, stream>>>(Qb, Kbuf, Vt, Ob);

    dim3 g3(64, 8);   // m-tile fastest for proj GEMM too
    gemm_nt<1><<<g3, 256, 0, stream>>>(Ob, wob, nullptr, nullptr, nullptr, out, bo, 1024);
}